// Round 9
// baseline (82.634 us; speedup 1.0000x reference)
//
#include <hip/hip_runtime.h>
#include <math.h>

#define D        256
#define KNN      8
#define G        16           // grid cells per axis
#define NCELL    (G*G*G)
#define CS       0.625f       // cell size = 10/16, exactly representable
#define EPS_D2   2e-3f        // margin >> f32 rounding error of reference d2
#define ROWS     4            // rows per fused block (512 blocks -> 2/CU)
#define CAP      64           // fixed bin capacity (Poisson(12.2); P(>64)~1e-40)
#define SPILLMAX 50000        // spill can hold every point -> never drops

typedef unsigned long long u64;

// orderable-float transform: monotonic u32 for any f32 (handles negatives)
__device__ __forceinline__ unsigned enc_f32(float f) {
    unsigned b = __float_as_uint(f);
    return b ^ ((unsigned)(((int)b) >> 31) | 0x80000000u);
}
__device__ __forceinline__ float dec_f32(unsigned t) {
    unsigned m = (unsigned)(((int)t) >> 31);
    return __uint_as_float(t ^ (0x80000000u | ~m));
}
__device__ __forceinline__ u64 mkkey(float d2, int j) {
    return ((u64)enc_f32(d2) << 32) | (u64)(unsigned)j;
}
__device__ __forceinline__ int cell_of(float x) {
    int c = (int)(x * 1.6f);
    return c < 0 ? 0 : (c > G-1 ? G-1 : c);
}

// ---------------------------------------------------------------------------
// Grid build: zero (cnt + spill_cnt), scatter into fixed-capacity bins with
// exact spill list.
// ---------------------------------------------------------------------------
__global__ __launch_bounds__(256) void zero_bins(int4* __restrict__ cnt4,
                                                 int* __restrict__ spill_cnt)
{
    const int t = blockIdx.x * 256 + threadIdx.x;   // 4 blocks -> t < 1024
    cnt4[t] = make_int4(0, 0, 0, 0);
    if (t == 0) *spill_cnt = 0;
}

__global__ __launch_bounds__(256) void scatter_bins(const float* __restrict__ spc,
                                                    int* __restrict__ cnt,
                                                    float4* __restrict__ bins,
                                                    int* __restrict__ spill_cnt,
                                                    float4* __restrict__ spill, int N)
{
    const int j = blockIdx.x * 256 + threadIdx.x;
    if (j >= N) return;
    const float px = spc[3*j+0], py = spc[3*j+1], pz = spc[3*j+2];
    const int cell = cell_of(px) | (cell_of(py) << 4) | (cell_of(pz) << 8);
    const float4 p = make_float4(px, py, pz, __int_as_float(j));
    const int pos = atomicAdd(&cnt[cell], 1);
    if (pos < CAP) bins[cell*CAP + pos] = p;
    else {
        const int sp = atomicAdd(spill_cnt, 1);
        if (sp < SPILLMAX) spill[sp] = p;
    }
}

// ---------------------------------------------------------------------------
// KNN helpers
// ---------------------------------------------------------------------------
#define INSERT8(xk)                                                            \
    if ((xk) < k7) {                                                           \
        const bool c0 = (xk) < k0, c1 = (xk) < k1, c2 = (xk) < k2,             \
                   c3 = (xk) < k3, c4 = (xk) < k4, c5 = (xk) < k5,             \
                   c6 = (xk) < k6;                                             \
        k7 = c6 ? k6 : (xk);                                                   \
        k6 = c5 ? k5 : (c6 ? (xk) : k6);                                       \
        k5 = c4 ? k4 : (c5 ? (xk) : k5);                                       \
        k4 = c3 ? k3 : (c4 ? (xk) : k4);                                       \
        k3 = c2 ? k2 : (c3 ? (xk) : k3);                                       \
        k2 = c1 ? k1 : (c2 ? (xk) : k2);                                       \
        k1 = c0 ? k0 : (c1 ? (xk) : k1);                                       \
        k0 = c0 ? (xk) : k0;                                                   \
    }

// bit-exact np/BLAS f32 d2: dot = fma(qz,pz, fma(qy,py, fl(qx*px)));
//                           d2  = (sq - fl(2*dot)) + sp
#define SCORE(p)                                                               \
    {                                                                          \
        const float sp  = __fadd_rn(__fadd_rn(__fmul_rn((p).x,(p).x),          \
                                  __fmul_rn((p).y,(p).y)), __fmul_rn((p).z,(p).z)); \
        const float dot = __fmaf_rn(qz,(p).z, __fmaf_rn(qy,(p).y, __fmul_rn(qx,(p).x))); \
        const float d2  = __fadd_rn(__fsub_rn(sq, __fmul_rn(2.0f, dot)), sp);  \
        const u64 xk = mkkey(d2, __float_as_int((p).w));                       \
        INSERT8(xk)                                                            \
    }

__device__ __forceinline__ void scan_cell_bins(int cell, const float4* __restrict__ bins,
                                               const int* __restrict__ cnt,
                                               float qx, float qy, float qz, float sq,
                                               u64& k0, u64& k1, u64& k2, u64& k3,
                                               u64& k4, u64& k5, u64& k6, u64& k7)
{
    const int n = min(cnt[cell], CAP);
    const int st = cell * CAP;
    for (int i = 0; i < n; ++i) {
        const float4 p = bins[st + i];
        SCORE(p)
    }
}

__device__ __forceinline__ void wave_merge8(int l, u64& k0, u64& k1, u64& k2, u64& k3,
                                            u64& k4, u64& k5, u64& k6, u64& k7,
                                            u64& mine, u64& worst)
{
#pragma unroll
    for (int rd = 0; rd < KNN; ++rd) {
        u64 m = k0;
#pragma unroll
        for (int o = 32; o; o >>= 1) {
            const u64 t = __shfl_xor(m, o);
            if (t < m) m = t;
        }
        if (k0 == m) {   // owner pops its sorted list
            k0 = k1; k1 = k2; k2 = k3; k3 = k4; k4 = k5; k5 = k6; k6 = k7;
            k7 = ~0ull;
        }
        if (l == rd) mine = m;
        if (rd == KNN-1) worst = m;   // wave-uniform
    }
}

// ---------------------------------------------------------------------------
// KNN: one wave per query, single-shot 4x4x4 cell block (1 cell/lane) +
// spill scan (normally zero-trip); exact full-grid fallback (prob ~0).
// ---------------------------------------------------------------------------
__global__ __launch_bounds__(64) void knn_grid(const float* __restrict__ qpos,
                                               const float4* __restrict__ bins,
                                               const int* __restrict__ cnt,
                                               const int* __restrict__ spill_cnt,
                                               const float4* __restrict__ spill,
                                               int* __restrict__ idx_out)
{
    const int q = blockIdx.x;
    const int l = threadIdx.x;
    const float qx = qpos[3*q+0], qy = qpos[3*q+1], qz = qpos[3*q+2];
    const float sq = __fadd_rn(__fadd_rn(__fmul_rn(qx,qx), __fmul_rn(qy,qy)),
                               __fmul_rn(qz,qz));
    const int cx = cell_of(qx), cy = cell_of(qy), cz = cell_of(qz);

    auto bstart = [](int c, float coord) {
        const float f = coord * 1.6f - (float)c;
        int b = c + ((f < 0.5f) ? -2 : -1);
        return b < 0 ? 0 : (b > G-4 ? G-4 : b);
    };
    const int bx = bstart(cx, qx), by = bstart(cy, qy), bz = bstart(cz, qz);

    u64 k0 = ~0ull, k1 = ~0ull, k2 = ~0ull, k3 = ~0ull,
        k4 = ~0ull, k5 = ~0ull, k6 = ~0ull, k7 = ~0ull;

    {   // lane l -> one cell of the 4x4x4 block
        const int x = bx + (l & 3), y = by + ((l >> 2) & 3), z = bz + (l >> 4);
        scan_cell_bins(x | (y << 4) | (z << 8), bins, cnt, qx, qy, qz, sq,
                       k0, k1, k2, k3, k4, k5, k6, k7);
    }
    {   // spill list (exactness; normally empty)
        const int ns = min(*spill_cnt, SPILLMAX);
        for (int i = l; i < ns; i += 64) { const float4 p = spill[i]; SCORE(p) }
    }

    u64 mine = ~0ull, worst = ~0ull;
    wave_merge8(l, k0, k1, k2, k3, k4, k5, k6, k7, mine, worst);

    const float w8 = dec_f32((unsigned)(worst >> 32));   // NaN if <8 cands
    float dmin = INFINITY;
    if (bx > 0)     dmin = fminf(dmin, qx - (float)bx * CS);
    if (bx + 4 < G) dmin = fminf(dmin, (float)(bx + 4) * CS - qx);
    if (by > 0)     dmin = fminf(dmin, qy - (float)by * CS);
    if (by + 4 < G) dmin = fminf(dmin, (float)(by + 4) * CS - qy);
    if (bz > 0)     dmin = fminf(dmin, qz - (float)bz * CS);
    if (bz + 4 < G) dmin = fminf(dmin, (float)(bz + 4) * CS - qz);

    if (!(w8 + EPS_D2 <= dmin * dmin)) {
        k0 = (l < KNN) ? mine : ~0ull;
        k1 = ~0ull; k2 = ~0ull; k3 = ~0ull; k4 = ~0ull; k5 = ~0ull; k6 = ~0ull; k7 = ~0ull;
        for (int c = l; c < NCELL; c += 64) {
            const int x = c & 15, y = (c >> 4) & 15, z = c >> 8;
            if (x >= bx && x < bx+4 && y >= by && y < by+4 && z >= bz && z < bz+4) continue;
            scan_cell_bins(c, bins, cnt, qx, qy, qz, sq, k0, k1, k2, k3, k4, k5, k6, k7);
        }
        wave_merge8(l, k0, k1, k2, k3, k4, k5, k6, k7, mine, worst);
    }

    if (l < KNN) idx_out[q*KNN + l] = (int)(unsigned)(mine & 0xffffffffu);
}

// ---------------------------------------------------------------------------
// Fused main, 4-row tile, 512 threads (8 waves), 2-way K-split:
//   q    = query @ w_q^T
//   gate = softmax(q @ w_k^T + w_b);  fbar = sum_j gate_j * feats[idx_j]
//   w    = (fbar @ w_v^T) * q
//   out  = LN(w @ w_o^T + query) * gamma + beta
// LDS = 20 KB -> multiple blocks/CU; 512 blocks = 2/CU so barriers in one
// block overlap compute in the other.
// ---------------------------------------------------------------------------
__global__ __launch_bounds__(512) void fused_main(const float* __restrict__ query,
                                                  const float* __restrict__ w_q,
                                                  const float* __restrict__ w_k,
                                                  const float* __restrict__ w_b,
                                                  const float* __restrict__ feats,
                                                  const int* __restrict__ idx,
                                                  const float* __restrict__ w_v,
                                                  const float* __restrict__ w_o,
                                                  const float* __restrict__ gmm,
                                                  const float* __restrict__ bta,
                                                  float* __restrict__ out)
{
    __shared__ float a_tile[ROWS][D];       // query rows (kept for residual)
    __shared__ float part[ROWS][D];         // K-split partial (h==1)
    __shared__ float q_tile[ROWS][D];
    __shared__ float f_tile[ROWS][D];       // fbar
    __shared__ float w_tile[ROWS][D];

    const int r0  = blockIdx.x * ROWS;
    const int tid = threadIdx.x;
    const int c = tid & 255, h = tid >> 8;           // h in {0,1}, wave-uniform
    const int wave = tid >> 6, lane = tid & 63;

    if (tid < 256)
        ((float4*)&a_tile[0][0])[tid] = ((const float4*)(query + (size_t)r0 * D))[tid];
    __syncthreads();

    float acc[ROWS];

    // ---- GEMM 1: q = query @ w_q^T (K-split half h) ----
#pragma unroll
    for (int r = 0; r < ROWS; ++r) acc[r] = 0.f;
    {
        const float4* W4 = (const float4*)(w_q + (size_t)c * D + h * 128);
        for (int k4 = 0; k4 < 32; ++k4) {
            const float4 w = W4[k4];
#pragma unroll
            for (int r = 0; r < ROWS; ++r) {
                const float4 a = *(const float4*)&a_tile[r][h*128 + k4*4];
                acc[r] = fmaf(a.x, w.x, fmaf(a.y, w.y, fmaf(a.z, w.z, fmaf(a.w, w.w, acc[r]))));
            }
        }
    }
    if (h) {
#pragma unroll
        for (int r = 0; r < ROWS; ++r) part[r][c] = acc[r];
    }
    __syncthreads();
    if (h == 0) {
#pragma unroll
        for (int r = 0; r < ROWS; ++r) q_tile[r][c] = acc[r] + part[r][c];
    }
    __syncthreads();

    // ---- gate + gather: wave w -> row w (waves 4..7 pass through) ----
    if (wave < ROWS) {
        const int row = r0 + wave;
        const float4 qv = *(const float4*)&q_tile[wave][lane*4];

        float logit[KNN];
#pragma unroll
        for (int j = 0; j < KNN; ++j) {
            const float4 w = *(const float4*)&w_k[(size_t)j*D + lane*4];
            logit[j] = fmaf(qv.x, w.x, fmaf(qv.y, w.y, fmaf(qv.z, w.z, qv.w*w.w)));
        }
#pragma unroll
        for (int o = 32; o; o >>= 1) {
#pragma unroll
            for (int j = 0; j < KNN; ++j) logit[j] += __shfl_xor(logit[j], o);
        }
#pragma unroll
        for (int j = 0; j < KNN; ++j) logit[j] += w_b[j];

        float m = logit[0];
#pragma unroll
        for (int j = 1; j < KNN; ++j) m = fmaxf(m, logit[j]);
        float e[KNN]; float ssum = 0.f;
#pragma unroll
        for (int j = 0; j < KNN; ++j) { e[j] = expf(logit[j] - m); ssum += e[j]; }
        const float inv = 1.f / ssum;

        int ids[KNN];
#pragma unroll
        for (int j = 0; j < KNN; ++j) ids[j] = idx[row*KNN + j];

        float4 acc4 = make_float4(0.f, 0.f, 0.f, 0.f);
#pragma unroll
        for (int j = 0; j < KNN; ++j) {
            const float gj = e[j] * inv;
            const float4 f = *(const float4*)&feats[(size_t)ids[j]*D + lane*4];
            acc4.x = fmaf(gj, f.x, acc4.x);
            acc4.y = fmaf(gj, f.y, acc4.y);
            acc4.z = fmaf(gj, f.z, acc4.z);
            acc4.w = fmaf(gj, f.w, acc4.w);
        }
        *(float4*)&f_tile[wave][lane*4] = acc4;
    }
    __syncthreads();

    // ---- GEMM 2: w = (fbar @ w_v^T) * q ----
#pragma unroll
    for (int r = 0; r < ROWS; ++r) acc[r] = 0.f;
    {
        const float4* W4 = (const float4*)(w_v + (size_t)c * D + h * 128);
        for (int k4 = 0; k4 < 32; ++k4) {
            const float4 w = W4[k4];
#pragma unroll
            for (int r = 0; r < ROWS; ++r) {
                const float4 a = *(const float4*)&f_tile[r][h*128 + k4*4];
                acc[r] = fmaf(a.x, w.x, fmaf(a.y, w.y, fmaf(a.z, w.z, fmaf(a.w, w.w, acc[r]))));
            }
        }
    }
    if (h) {
#pragma unroll
        for (int r = 0; r < ROWS; ++r) part[r][c] = acc[r];
    }
    __syncthreads();
    if (h == 0) {
#pragma unroll
        for (int r = 0; r < ROWS; ++r)
            w_tile[r][c] = (acc[r] + part[r][c]) * q_tile[r][c];
    }
    __syncthreads();

    // ---- GEMM 3: out_pre = w @ w_o^T + query ----
#pragma unroll
    for (int r = 0; r < ROWS; ++r) acc[r] = 0.f;
    {
        const float4* W4 = (const float4*)(w_o + (size_t)c * D + h * 128);
        for (int k4 = 0; k4 < 32; ++k4) {
            const float4 w = W4[k4];
#pragma unroll
            for (int r = 0; r < ROWS; ++r) {
                const float4 a = *(const float4*)&w_tile[r][h*128 + k4*4];
                acc[r] = fmaf(a.x, w.x, fmaf(a.y, w.y, fmaf(a.z, w.z, fmaf(a.w, w.w, acc[r]))));
            }
        }
    }
    if (h) {
#pragma unroll
        for (int r = 0; r < ROWS; ++r) part[r][c] = acc[r];
    }
    __syncthreads();
    if (h == 0) {
#pragma unroll
        for (int r = 0; r < ROWS; ++r)
            a_tile[r][c] = acc[r] + part[r][c] + a_tile[r][c];   // + residual
    }
    __syncthreads();

    // ---- LayerNorm: wave w -> row w ----
    if (wave < ROWS) {
        const float4 v = *(const float4*)&a_tile[wave][lane*4];
        float s  = (v.x + v.y) + (v.z + v.w);
        float s2 = fmaf(v.x, v.x, fmaf(v.y, v.y, fmaf(v.z, v.z, v.w*v.w)));
#pragma unroll
        for (int o = 32; o; o >>= 1) { s += __shfl_xor(s, o); s2 += __shfl_xor(s2, o); }
        const float mu  = s * (1.f/256.f);
        const float var = fmaf(s2, 1.f/256.f, -mu*mu);
        const float rs  = rsqrtf(var + 1e-5f);
        const float4 g = *(const float4*)&gmm[lane*4];
        const float4 b = *(const float4*)&bta[lane*4];
        float4 o4;
        o4.x = (v.x - mu) * rs * g.x + b.x;
        o4.y = (v.y - mu) * rs * g.y + b.y;
        o4.z = (v.z - mu) * rs * g.z + b.z;
        o4.w = (v.w - mu) * rs * g.w + b.w;
        *(float4*)&out[(size_t)(r0+wave)*D + lane*4] = o4;
    }
}

// ---------------------------------------------------------------------------
extern "C" void kernel_launch(void* const* d_in, const int* in_sizes, int n_in,
                              void* d_out, int out_size, void* d_ws, size_t ws_size,
                              hipStream_t stream)
{
    const float* query = (const float*)d_in[0];
    const float* qpos  = (const float*)d_in[1];
    const float* feats = (const float*)d_in[2];
    const float* spc   = (const float*)d_in[3];
    const float* w_q   = (const float*)d_in[4];
    const float* w_v   = (const float*)d_in[5];
    const float* w_o   = (const float*)d_in[6];
    const float* w_k   = (const float*)d_in[7];
    const float* w_b   = (const float*)d_in[8];
    const float* gamma = (const float*)d_in[9];
    const float* beta  = (const float*)d_in[10];

    const int Nq = in_sizes[0] / D;   // 2048
    const int N  = in_sizes[2] / D;   // 50000

    char* ws = (char*)d_ws;
    size_t off = 0;
    int* cnt = (int*)(ws + off);          off += ((size_t)NCELL * 4 + 255) & ~(size_t)255;
    int* spill_cnt = (int*)(ws + off);    off += 256;
    float4* bins = (float4*)(ws + off);   off += ((size_t)NCELL * CAP * 16 + 255) & ~(size_t)255;
    float4* spill = (float4*)(ws + off);  off += ((size_t)SPILLMAX * 16 + 255) & ~(size_t)255;
    int* idx = (int*)(ws + off);          off += ((size_t)Nq * KNN * 4 + 255) & ~(size_t)255;

    zero_bins<<<4, 256, 0, stream>>>((int4*)cnt, spill_cnt);
    scatter_bins<<<(N + 255)/256, 256, 0, stream>>>(spc, cnt, bins, spill_cnt, spill, N);
    knn_grid<<<Nq, 64, 0, stream>>>(qpos, bins, cnt, spill_cnt, spill, idx);
    fused_main<<<Nq/ROWS, 512, 0, stream>>>(query, w_q, w_k, w_b, feats, idx,
                                            w_v, w_o, gamma, beta, (float*)d_out);
}

// Round 10
// 68.107 us; speedup vs baseline: 1.2133x; 1.2133x over previous
//
#include <hip/hip_runtime.h>
#include <math.h>

#define D        256
#define KNN      8
#define G        16           // grid cells per axis
#define NCELL    (G*G*G)
#define CS       0.625f       // cell size = 10/16, exactly representable
#define EPS_D2   2e-3f        // margin >> f32 rounding error of reference d2
#define ROWS     8            // rows per fused block (256 blocks, 16 waves)
#define CAP      64           // fixed bin capacity (Poisson(12.2); P(>64)~1e-40)
#define SPILLMAX 50000        // spill can hold every point -> never drops

typedef unsigned long long u64;

// orderable-float transform: monotonic u32 for any f32 (handles negatives)
__device__ __forceinline__ unsigned enc_f32(float f) {
    unsigned b = __float_as_uint(f);
    return b ^ ((unsigned)(((int)b) >> 31) | 0x80000000u);
}
__device__ __forceinline__ float dec_f32(unsigned t) {
    unsigned m = (unsigned)(((int)t) >> 31);
    return __uint_as_float(t ^ (0x80000000u | ~m));
}
__device__ __forceinline__ u64 mkkey(float d2, int j) {
    return ((u64)enc_f32(d2) << 32) | (u64)(unsigned)j;
}
__device__ __forceinline__ int cell_of(float x) {
    int c = (int)(x * 1.6f);
    return c < 0 ? 0 : (c > G-1 ? G-1 : c);
}

// ---------------------------------------------------------------------------
// Grid build: zero (cnt + spill_cnt), scatter into fixed-capacity bins with
// exact spill list.
// ---------------------------------------------------------------------------
__global__ __launch_bounds__(256) void zero_bins(int4* __restrict__ cnt4,
                                                 int* __restrict__ spill_cnt)
{
    const int t = blockIdx.x * 256 + threadIdx.x;   // 4 blocks -> t < 1024
    cnt4[t] = make_int4(0, 0, 0, 0);
    if (t == 0) *spill_cnt = 0;
}

__global__ __launch_bounds__(256) void scatter_bins(const float* __restrict__ spc,
                                                    int* __restrict__ cnt,
                                                    float4* __restrict__ bins,
                                                    int* __restrict__ spill_cnt,
                                                    float4* __restrict__ spill, int N)
{
    const int j = blockIdx.x * 256 + threadIdx.x;
    if (j >= N) return;
    const float px = spc[3*j+0], py = spc[3*j+1], pz = spc[3*j+2];
    const int cell = cell_of(px) | (cell_of(py) << 4) | (cell_of(pz) << 8);
    const float4 p = make_float4(px, py, pz, __int_as_float(j));
    const int pos = atomicAdd(&cnt[cell], 1);
    if (pos < CAP) bins[cell*CAP + pos] = p;
    else {
        const int sp = atomicAdd(spill_cnt, 1);
        if (sp < SPILLMAX) spill[sp] = p;
    }
}

// ---------------------------------------------------------------------------
// KNN helpers
// ---------------------------------------------------------------------------
#define INSERT8(xk)                                                            \
    if ((xk) < k7) {                                                           \
        const bool c0 = (xk) < k0, c1 = (xk) < k1, c2 = (xk) < k2,             \
                   c3 = (xk) < k3, c4 = (xk) < k4, c5 = (xk) < k5,             \
                   c6 = (xk) < k6;                                             \
        k7 = c6 ? k6 : (xk);                                                   \
        k6 = c5 ? k5 : (c6 ? (xk) : k6);                                       \
        k5 = c4 ? k4 : (c5 ? (xk) : k5);                                       \
        k4 = c3 ? k3 : (c4 ? (xk) : k4);                                       \
        k3 = c2 ? k2 : (c3 ? (xk) : k3);                                       \
        k2 = c1 ? k1 : (c2 ? (xk) : k2);                                       \
        k1 = c0 ? k0 : (c1 ? (xk) : k1);                                       \
        k0 = c0 ? (xk) : k0;                                                   \
    }

// bit-exact np/BLAS f32 d2: dot = fma(qz,pz, fma(qy,py, fl(qx*px)));
//                           d2  = (sq - fl(2*dot)) + sp
#define SCORE(p)                                                               \
    {                                                                          \
        const float sp  = __fadd_rn(__fadd_rn(__fmul_rn((p).x,(p).x),          \
                                  __fmul_rn((p).y,(p).y)), __fmul_rn((p).z,(p).z)); \
        const float dot = __fmaf_rn(qz,(p).z, __fmaf_rn(qy,(p).y, __fmul_rn(qx,(p).x))); \
        const float d2  = __fadd_rn(__fsub_rn(sq, __fmul_rn(2.0f, dot)), sp);  \
        const u64 xk = mkkey(d2, __float_as_int((p).w));                       \
        INSERT8(xk)                                                            \
    }

__device__ __forceinline__ void scan_cell_bins(int cell, const float4* __restrict__ bins,
                                               const int* __restrict__ cnt,
                                               float qx, float qy, float qz, float sq,
                                               u64& k0, u64& k1, u64& k2, u64& k3,
                                               u64& k4, u64& k5, u64& k6, u64& k7)
{
    const int n = min(cnt[cell], CAP);
    const int st = cell * CAP;
    for (int i = 0; i < n; ++i) {
        const float4 p = bins[st + i];
        SCORE(p)
    }
}

__device__ __forceinline__ void wave_merge8(int l, u64& k0, u64& k1, u64& k2, u64& k3,
                                            u64& k4, u64& k5, u64& k6, u64& k7,
                                            u64& mine, u64& worst)
{
#pragma unroll
    for (int rd = 0; rd < KNN; ++rd) {
        u64 m = k0;
#pragma unroll
        for (int o = 32; o; o >>= 1) {
            const u64 t = __shfl_xor(m, o);
            if (t < m) m = t;
        }
        if (k0 == m) {   // owner pops its sorted list
            k0 = k1; k1 = k2; k2 = k3; k3 = k4; k4 = k5; k5 = k6; k6 = k7;
            k7 = ~0ull;
        }
        if (l == rd) mine = m;
        if (rd == KNN-1) worst = m;   // wave-uniform
    }
}

// ---------------------------------------------------------------------------
// KNN: one wave per query, single-shot 4x4x4 cell block (1 cell/lane) +
// spill scan (normally zero-trip); exact full-grid fallback (prob ~0).
// ---------------------------------------------------------------------------
__global__ __launch_bounds__(64) void knn_grid(const float* __restrict__ qpos,
                                               const float4* __restrict__ bins,
                                               const int* __restrict__ cnt,
                                               const int* __restrict__ spill_cnt,
                                               const float4* __restrict__ spill,
                                               int* __restrict__ idx_out)
{
    const int q = blockIdx.x;
    const int l = threadIdx.x;
    const float qx = qpos[3*q+0], qy = qpos[3*q+1], qz = qpos[3*q+2];
    const float sq = __fadd_rn(__fadd_rn(__fmul_rn(qx,qx), __fmul_rn(qy,qy)),
                               __fmul_rn(qz,qz));
    const int cx = cell_of(qx), cy = cell_of(qy), cz = cell_of(qz);

    auto bstart = [](int c, float coord) {
        const float f = coord * 1.6f - (float)c;
        int b = c + ((f < 0.5f) ? -2 : -1);
        return b < 0 ? 0 : (b > G-4 ? G-4 : b);
    };
    const int bx = bstart(cx, qx), by = bstart(cy, qy), bz = bstart(cz, qz);

    u64 k0 = ~0ull, k1 = ~0ull, k2 = ~0ull, k3 = ~0ull,
        k4 = ~0ull, k5 = ~0ull, k6 = ~0ull, k7 = ~0ull;

    {   // lane l -> one cell of the 4x4x4 block
        const int x = bx + (l & 3), y = by + ((l >> 2) & 3), z = bz + (l >> 4);
        scan_cell_bins(x | (y << 4) | (z << 8), bins, cnt, qx, qy, qz, sq,
                       k0, k1, k2, k3, k4, k5, k6, k7);
    }
    {   // spill list (exactness; normally empty)
        const int ns = min(*spill_cnt, SPILLMAX);
        for (int i = l; i < ns; i += 64) { const float4 p = spill[i]; SCORE(p) }
    }

    u64 mine = ~0ull, worst = ~0ull;
    wave_merge8(l, k0, k1, k2, k3, k4, k5, k6, k7, mine, worst);

    const float w8 = dec_f32((unsigned)(worst >> 32));   // NaN if <8 cands
    float dmin = INFINITY;
    if (bx > 0)     dmin = fminf(dmin, qx - (float)bx * CS);
    if (bx + 4 < G) dmin = fminf(dmin, (float)(bx + 4) * CS - qx);
    if (by > 0)     dmin = fminf(dmin, qy - (float)by * CS);
    if (by + 4 < G) dmin = fminf(dmin, (float)(by + 4) * CS - qy);
    if (bz > 0)     dmin = fminf(dmin, qz - (float)bz * CS);
    if (bz + 4 < G) dmin = fminf(dmin, (float)(bz + 4) * CS - qz);

    if (!(w8 + EPS_D2 <= dmin * dmin)) {
        k0 = (l < KNN) ? mine : ~0ull;
        k1 = ~0ull; k2 = ~0ull; k3 = ~0ull; k4 = ~0ull; k5 = ~0ull; k6 = ~0ull; k7 = ~0ull;
        for (int c = l; c < NCELL; c += 64) {
            const int x = c & 15, y = (c >> 4) & 15, z = c >> 8;
            if (x >= bx && x < bx+4 && y >= by && y < by+4 && z >= bz && z < bz+4) continue;
            scan_cell_bins(c, bins, cnt, qx, qy, qz, sq, k0, k1, k2, k3, k4, k5, k6, k7);
        }
        wave_merge8(l, k0, k1, k2, k3, k4, k5, k6, k7, mine, worst);
    }

    if (l < KNN) idx_out[q*KNN + l] = (int)(unsigned)(mine & 0xffffffffu);
}

// ---------------------------------------------------------------------------
// Fused main, 8-row tile, 1024 threads (16 waves), 4-way K-split.
// Weight quarters are REGISTER-STAGED (wreg[16] burst, 16 loads in flight)
// so L2 latency is paid once per GEMM, not once per k4 iteration.
//   q    = query @ w_q^T
//   gate = softmax(q @ w_k^T + w_b);  fbar = sum_j gate_j * feats[idx_j]
//   w    = (fbar @ w_v^T) * q
//   out  = LN(w @ w_o^T + query) * gamma + beta
// ---------------------------------------------------------------------------
__global__ __launch_bounds__(1024) void fused_main(const float* __restrict__ query,
                                                   const float* __restrict__ w_q,
                                                   const float* __restrict__ w_k,
                                                   const float* __restrict__ w_b,
                                                   const float* __restrict__ feats,
                                                   const int* __restrict__ idx,
                                                   const float* __restrict__ w_v,
                                                   const float* __restrict__ w_o,
                                                   const float* __restrict__ gmm,
                                                   const float* __restrict__ bta,
                                                   float* __restrict__ out)
{
    __shared__ float a_tile[ROWS][D];       // query rows (kept for residual)
    __shared__ float part[3][ROWS][D];      // K-split partials
    __shared__ float q_tile[ROWS][D];
    __shared__ float f_tile[ROWS][D];       // fbar
    __shared__ float w_tile[ROWS][D];

    const int r0  = blockIdx.x * ROWS;
    const int tid = threadIdx.x;
    const int c = tid & 255, h = tid >> 8;           // h in 0..3, wave-uniform
    const int wave = tid >> 6, lane = tid & 63;

    if (tid < 512)
        ((float4*)&a_tile[0][0])[tid] = ((const float4*)(query + (size_t)r0 * D))[tid];

    float acc[ROWS];
    float4 wreg[16];

    // ---- GEMM 1: q = query @ w_q^T (K-quarter h) ----
    {
        const float4* W4 = (const float4*)(w_q + (size_t)c * D + h * 64);
#pragma unroll
        for (int k4 = 0; k4 < 16; ++k4) wreg[k4] = W4[k4];   // burst: 16 in flight
    }
    __syncthreads();
#pragma unroll
    for (int r = 0; r < ROWS; ++r) acc[r] = 0.f;
#pragma unroll
    for (int k4 = 0; k4 < 16; ++k4) {
        const float4 w = wreg[k4];
#pragma unroll
        for (int r = 0; r < ROWS; ++r) {
            const float4 a = *(const float4*)&a_tile[r][h*64 + k4*4];
            acc[r] = fmaf(a.x, w.x, fmaf(a.y, w.y, fmaf(a.z, w.z, fmaf(a.w, w.w, acc[r]))));
        }
    }
    if (h) {
#pragma unroll
        for (int r = 0; r < ROWS; ++r) part[h-1][r][c] = acc[r];
    }
    __syncthreads();
    if (h == 0) {
#pragma unroll
        for (int r = 0; r < ROWS; ++r)
            q_tile[r][c] = acc[r] + part[0][r][c] + part[1][r][c] + part[2][r][c];
    }

    // ---- prefetch GEMM 2 weights (covered by gather/softmax phase) ----
    {
        const float4* W4 = (const float4*)(w_v + (size_t)c * D + h * 64);
#pragma unroll
        for (int k4 = 0; k4 < 16; ++k4) wreg[k4] = W4[k4];
    }
    __syncthreads();

    // ---- gate + gather: wave w -> row w (waves 8..15 pass through) ----
    if (wave < ROWS) {
        const int row = r0 + wave;
        const float4 qv = *(const float4*)&q_tile[wave][lane*4];

        float logit[KNN];
#pragma unroll
        for (int j = 0; j < KNN; ++j) {
            const float4 w = *(const float4*)&w_k[(size_t)j*D + lane*4];
            logit[j] = fmaf(qv.x, w.x, fmaf(qv.y, w.y, fmaf(qv.z, w.z, qv.w*w.w)));
        }
#pragma unroll
        for (int o = 32; o; o >>= 1) {
#pragma unroll
            for (int j = 0; j < KNN; ++j) logit[j] += __shfl_xor(logit[j], o);
        }
#pragma unroll
        for (int j = 0; j < KNN; ++j) logit[j] += w_b[j];

        float m = logit[0];
#pragma unroll
        for (int j = 1; j < KNN; ++j) m = fmaxf(m, logit[j]);
        float e[KNN]; float ssum = 0.f;
#pragma unroll
        for (int j = 0; j < KNN; ++j) { e[j] = expf(logit[j] - m); ssum += e[j]; }
        const float inv = 1.f / ssum;

        int ids[KNN];
#pragma unroll
        for (int j = 0; j < KNN; ++j) ids[j] = idx[row*KNN + j];

        float4 acc4 = make_float4(0.f, 0.f, 0.f, 0.f);
#pragma unroll
        for (int j = 0; j < KNN; ++j) {
            const float gj = e[j] * inv;
            const float4 f = *(const float4*)&feats[(size_t)ids[j]*D + lane*4];
            acc4.x = fmaf(gj, f.x, acc4.x);
            acc4.y = fmaf(gj, f.y, acc4.y);
            acc4.z = fmaf(gj, f.z, acc4.z);
            acc4.w = fmaf(gj, f.w, acc4.w);
        }
        *(float4*)&f_tile[wave][lane*4] = acc4;
    }
    __syncthreads();

    // ---- GEMM 2: w = (fbar @ w_v^T) * q ----
#pragma unroll
    for (int r = 0; r < ROWS; ++r) acc[r] = 0.f;
#pragma unroll
    for (int k4 = 0; k4 < 16; ++k4) {
        const float4 w = wreg[k4];
#pragma unroll
        for (int r = 0; r < ROWS; ++r) {
            const float4 a = *(const float4*)&f_tile[r][h*64 + k4*4];
            acc[r] = fmaf(a.x, w.x, fmaf(a.y, w.y, fmaf(a.z, w.z, fmaf(a.w, w.w, acc[r]))));
        }
    }
    // prefetch GEMM 3 weights (wreg dead after FMA loop above)
    {
        const float4* W4 = (const float4*)(w_o + (size_t)c * D + h * 64);
#pragma unroll
        for (int k4 = 0; k4 < 16; ++k4) wreg[k4] = W4[k4];
    }
    if (h) {
#pragma unroll
        for (int r = 0; r < ROWS; ++r) part[h-1][r][c] = acc[r];
    }
    __syncthreads();
    if (h == 0) {
#pragma unroll
        for (int r = 0; r < ROWS; ++r)
            w_tile[r][c] = (acc[r] + part[0][r][c] + part[1][r][c] + part[2][r][c])
                           * q_tile[r][c];
    }
    __syncthreads();

    // ---- GEMM 3: out_pre = w @ w_o^T + query ----
#pragma unroll
    for (int r = 0; r < ROWS; ++r) acc[r] = 0.f;
#pragma unroll
    for (int k4 = 0; k4 < 16; ++k4) {
        const float4 w = wreg[k4];
#pragma unroll
        for (int r = 0; r < ROWS; ++r) {
            const float4 a = *(const float4*)&w_tile[r][h*64 + k4*4];
            acc[r] = fmaf(a.x, w.x, fmaf(a.y, w.y, fmaf(a.z, w.z, fmaf(a.w, w.w, acc[r]))));
        }
    }
    if (h) {
#pragma unroll
        for (int r = 0; r < ROWS; ++r) part[h-1][r][c] = acc[r];
    }
    __syncthreads();
    if (h == 0) {
#pragma unroll
        for (int r = 0; r < ROWS; ++r)
            a_tile[r][c] = acc[r] + part[0][r][c] + part[1][r][c] + part[2][r][c]
                           + a_tile[r][c];     // + residual (a_tile holds query)
    }
    __syncthreads();

    // ---- LayerNorm: wave w -> row w ----
    if (wave < ROWS) {
        const float4 v = *(const float4*)&a_tile[wave][lane*4];
        float s  = (v.x + v.y) + (v.z + v.w);
        float s2 = fmaf(v.x, v.x, fmaf(v.y, v.y, fmaf(v.z, v.z, v.w*v.w)));
#pragma unroll
        for (int o = 32; o; o >>= 1) { s += __shfl_xor(s, o); s2 += __shfl_xor(s2, o); }
        const float mu  = s * (1.f/256.f);
        const float var = fmaf(s2, 1.f/256.f, -mu*mu);
        const float rs  = rsqrtf(var + 1e-5f);
        const float4 g = *(const float4*)&gmm[lane*4];
        const float4 b = *(const float4*)&bta[lane*4];
        float4 o4;
        o4.x = (v.x - mu) * rs * g.x + b.x;
        o4.y = (v.y - mu) * rs * g.y + b.y;
        o4.z = (v.z - mu) * rs * g.z + b.z;
        o4.w = (v.w - mu) * rs * g.w + b.w;
        *(float4*)&out[(size_t)(r0+wave)*D + lane*4] = o4;
    }
}

// ---------------------------------------------------------------------------
extern "C" void kernel_launch(void* const* d_in, const int* in_sizes, int n_in,
                              void* d_out, int out_size, void* d_ws, size_t ws_size,
                              hipStream_t stream)
{
    const float* query = (const float*)d_in[0];
    const float* qpos  = (const float*)d_in[1];
    const float* feats = (const float*)d_in[2];
    const float* spc   = (const float*)d_in[3];
    const float* w_q   = (const float*)d_in[4];
    const float* w_v   = (const float*)d_in[5];
    const float* w_o   = (const float*)d_in[6];
    const float* w_k   = (const float*)d_in[7];
    const float* w_b   = (const float*)d_in[8];
    const float* gamma = (const float*)d_in[9];
    const float* beta  = (const float*)d_in[10];

    const int Nq = in_sizes[0] / D;   // 2048
    const int N  = in_sizes[2] / D;   // 50000

    char* ws = (char*)d_ws;
    size_t off = 0;
    int* cnt = (int*)(ws + off);          off += ((size_t)NCELL * 4 + 255) & ~(size_t)255;
    int* spill_cnt = (int*)(ws + off);    off += 256;
    float4* bins = (float4*)(ws + off);   off += ((size_t)NCELL * CAP * 16 + 255) & ~(size_t)255;
    float4* spill = (float4*)(ws + off);  off += ((size_t)SPILLMAX * 16 + 255) & ~(size_t)255;
    int* idx = (int*)(ws + off);          off += ((size_t)Nq * KNN * 4 + 255) & ~(size_t)255;

    zero_bins<<<4, 256, 0, stream>>>((int4*)cnt, spill_cnt);
    scatter_bins<<<(N + 255)/256, 256, 0, stream>>>(spc, cnt, bins, spill_cnt, spill, N);
    knn_grid<<<Nq, 64, 0, stream>>>(qpos, bins, cnt, spill_cnt, spill, idx);
    fused_main<<<Nq/ROWS, 1024, 0, stream>>>(query, w_q, w_k, w_b, feats, idx,
                                             w_v, w_o, gamma, beta, (float*)d_out);
}